// Round 1
// baseline (120.092 us; speedup 1.0000x reference)
//
#include <hip/hip_runtime.h>

// BoundaryAwareLoss: dice(pred,target) + bce(sigmoid(pred)*boundary, target*boundary)
// boundary = 15x15 dilate - erode of binary target (clipped windows at borders).
// BCE broadcast (B,H,W)*(B,1,H,W)->(B,B,H,W) factors per-pixel:
//   sum_{b1,b2} bd[b1,h,w]*f[b2,h,w] = cnt[h,w] * F[h,w]
// and bd==0 pixels contribute exactly 0 to the BCE sum.

#define BB   8
#define HH   544
#define WW   544
#define KK   15
#define PADR 7
#define TH   16
#define TW   32
#define SR   (TH + 2*PADR)   // 30 staged rows
#define SC   (TW + 2*PADR)   // 46 staged cols
#define SCP  48              // padded stage width

__global__ __launch_bounds__(256) void baloss_main(
    const float* __restrict__ pred, const float* __restrict__ targ,
    float* __restrict__ acc)
{
    __shared__ float sh_t[SR][SCP];
    __shared__ float hmx[SR][TW + 1];
    __shared__ float hmn[SR][TW + 1];
    __shared__ float red[4][4];

    const int tiles_x = WW / TW;               // 17
    const int tile_x  = blockIdx.x % tiles_x;
    const int tile_y  = blockIdx.x / tiles_x;
    const int x0 = tile_x * TW;
    const int y0 = tile_y * TH;
    const int tid = threadIdx.x;
    const int tx  = tid & 31;
    const int ty  = tid >> 5;                  // 0..7

    float sp = 0.f, st = 0.f, si = 0.f;
    float cnt0 = 0.f, cnt1 = 0.f, fs0 = 0.f, fs1 = 0.f;

    for (int b = 0; b < BB; ++b) {
        const float* tb = targ + (size_t)b * HH * WW;
        const float* pb = pred + (size_t)b * HH * WW;

        // stage target tile + halo, clamp-to-edge (== clipped-window min/max)
        for (int i = tid; i < SR * SC; i += 256) {
            int r = i / SC, c = i - r * SC;
            int gy = y0 - PADR + r; gy = gy < 0 ? 0 : (gy > HH - 1 ? HH - 1 : gy);
            int gx = x0 - PADR + c; gx = gx < 0 ? 0 : (gx > WW - 1 ? WW - 1 : gx);
            sh_t[r][c] = tb[gy * WW + gx];
        }
        __syncthreads();

        // horizontal 15-tap max/min
        for (int i = tid; i < SR * TW; i += 256) {
            int r = i >> 5, c = i & 31;
            float mx = sh_t[r][c], mn = mx;
            #pragma unroll
            for (int j = 1; j < KK; ++j) {
                float v = sh_t[r][c + j];
                mx = fmaxf(mx, v);
                mn = fminf(mn, v);
            }
            hmx[r][c] = mx;
            hmn[r][c] = mn;
        }
        __syncthreads();

        // vertical 15-tap + per-pixel BCE/dice terms (2 pixels/thread)
        #pragma unroll
        for (int k = 0; k < 2; ++k) {
            int ly = ty + k * 8;               // 0..15
            int gy = y0 + ly, gx = x0 + tx;
            float mx = hmx[ly][tx], mn = hmn[ly][tx];
            #pragma unroll
            for (int j = 1; j < KK; ++j) {
                mx = fmaxf(mx, hmx[ly + j][tx]);
                mn = fminf(mn, hmn[ly + j][tx]);
            }
            float bd = mx - mn;                // 0 or 1
            float p  = pb[gy * WW + gx];
            float tt = sh_t[ly + PADR][tx + PADR];
            sp += p;
            st += tt;
            si += p * tt;
            float s   = 1.f / (1.f + expf(-p));
            float lp  = fmaxf(logf(s),       -100.f);
            float l1p = fmaxf(logf(1.f - s), -100.f);
            float f   = tt * lp + (1.f - tt) * l1p;
            if (k == 0) { cnt0 += bd; fs0 += f; }
            else        { cnt1 += bd; fs1 += f; }
        }
        __syncthreads();   // LDS reused next b
    }

    float bsum = cnt0 * fs0 + cnt1 * fs1;

    // block reduction: wave shuffle then cross-wave via LDS
    #pragma unroll
    for (int off = 32; off > 0; off >>= 1) {
        sp   += __shfl_down(sp, off);
        st   += __shfl_down(st, off);
        si   += __shfl_down(si, off);
        bsum += __shfl_down(bsum, off);
    }
    int wave = tid >> 6, lane = tid & 63;
    if (lane == 0) {
        red[wave][0] = sp; red[wave][1] = st;
        red[wave][2] = si; red[wave][3] = bsum;
    }
    __syncthreads();
    if (tid == 0) {
        float a0 = 0.f, a1 = 0.f, a2 = 0.f, a3 = 0.f;
        #pragma unroll
        for (int w = 0; w < 4; ++w) {
            a0 += red[w][0]; a1 += red[w][1];
            a2 += red[w][2]; a3 += red[w][3];
        }
        atomicAdd(&acc[0], a0);
        atomicAdd(&acc[1], a1);
        atomicAdd(&acc[2], a2);
        atomicAdd(&acc[3], a3);
    }
}

__global__ void baloss_final(const float* __restrict__ acc, float* __restrict__ out)
{
    if (threadIdx.x == 0) {
        float sp = acc[0], st = acc[1], si = acc[2], bs = acc[3];
        float dice = 1.f - (2.f * si + 1.f) / (sp + st + 1.f);
        float bce  = -bs / (float)((long long)BB * BB * HH * WW);
        out[0] = dice + bce;
    }
}

extern "C" void kernel_launch(void* const* d_in, const int* in_sizes, int n_in,
                              void* d_out, int out_size, void* d_ws, size_t ws_size,
                              hipStream_t stream) {
    const float* pred = (const float*)d_in[0];
    const float* targ = (const float*)d_in[1];
    float* out = (float*)d_out;
    float* acc = (float*)d_ws;

    hipMemsetAsync(acc, 0, 4 * sizeof(float), stream);

    dim3 grid((HH / TH) * (WW / TW));   // 34*17 = 578 blocks
    baloss_main<<<grid, 256, 0, stream>>>(pred, targ, acc);
    baloss_final<<<1, 64, 0, stream>>>(acc, out);
}